// Round 6
// baseline (491.556 us; speedup 1.0000x reference)
//
#include <hip/hip_runtime.h>
#include <math.h>

#define N_NODES 50000
#define N_EDGES 800000
#define N_GRAPHS 64
#define F_INN 128
#define F_HID 192
#define F_OUTT 128
#define N_CLS 10

typedef short short8 __attribute__((ext_vector_type(8)));
typedef float f32x4 __attribute__((ext_vector_type(4)));

static __device__ inline unsigned short f2bf(float f) {
    unsigned int u = __float_as_uint(f);
    unsigned int r = (u + 0x7FFFu + ((u >> 16) & 1u)) >> 16;  // RNE
    return (unsigned short)r;
}
static __device__ inline float bf2f(unsigned short h) {
    return __uint_as_float(((unsigned int)h) << 16);
}

// ---------------- CSR build ----------------
__global__ void k_deg(const int* __restrict__ row, int* __restrict__ cnt,
                      int* __restrict__ rank) {
    int e = blockIdx.x * 256 + threadIdx.x;
    if (e < N_EDGES) rank[e] = atomicAdd(&cnt[row[e]], 1);
}

__global__ void k_scan1(const int* __restrict__ cnt, int* __restrict__ rp,
                        int* __restrict__ part, float* __restrict__ dis) {
    __shared__ int s[256];
    int base = blockIdx.x * 512;
    int i0 = base + 2 * threadIdx.x;
    int v0 = (i0 < N_NODES) ? cnt[i0] : 0;
    int v1 = (i0 + 1 < N_NODES) ? cnt[i0 + 1] : 0;
    if (i0 < N_NODES) dis[i0] = v0 > 0 ? rsqrtf((float)v0) : 0.f;
    if (i0 + 1 < N_NODES) dis[i0 + 1] = v1 > 0 ? rsqrtf((float)v1) : 0.f;
    int tsum = v0 + v1;
    s[threadIdx.x] = tsum;
    __syncthreads();
    for (int off = 1; off < 256; off <<= 1) {
        int val = (threadIdx.x >= off) ? s[threadIdx.x - off] : 0;
        __syncthreads();
        s[threadIdx.x] += val;
        __syncthreads();
    }
    int excl = s[threadIdx.x] - tsum;
    if (i0 < N_NODES) rp[i0] = excl;
    if (i0 + 1 < N_NODES) rp[i0 + 1] = excl + v0;
    if (threadIdx.x == 255) part[blockIdx.x] = s[255];
}

__global__ void k_scan3(int* __restrict__ rp, const int* __restrict__ part,
                        int nb) {
    __shared__ int s[128];
    int t = threadIdx.x;
    int b = blockIdx.x;
    if (t < 128) s[t] = (t < b && t < nb) ? part[t] : 0;
    __syncthreads();
    for (int off = 64; off > 0; off >>= 1) {
        if (t < off) s[t] += s[t + off];
        __syncthreads();
    }
    int add = s[0];
    int i0 = b * 512 + 2 * t;
    if (i0 < N_NODES) rp[i0] += add;
    if (i0 + 1 < N_NODES) rp[i0 + 1] += add;
    if (b == 0 && t == 0) rp[N_NODES] = N_EDGES;
}

// packed CSR payload: (col, weight-bits) int2 + u8 edge->graph stream (ge).
// CSR order is row-sorted and batch is node-sorted, so ge is NON-DECREASING
// along the edge array — k_gpool2 exploits this.
// ROUND-13 LESSON: never split into col + dis[] recompute (dependent load).
__global__ void k_scatter(const int* __restrict__ row, const int* __restrict__ col,
                          const float* __restrict__ dis, const int* __restrict__ rp,
                          const int* __restrict__ rank, const int* __restrict__ batch,
                          int2* __restrict__ cw, unsigned char* __restrict__ ge) {
    int e = blockIdx.x * 256 + threadIdx.x;
    if (e < N_EDGES) {
        int r = row[e], c = col[e];
        int pos = rp[r] + rank[e];
        int2 v;
        v.x = c;
        v.y = __float_as_int(-dis[r] * dis[c]);
        cw[pos] = v;
        ge[pos] = (unsigned char)batch[r];
    }
}

// ---------------- fused fp32->bf16 conversions + workspace zeroing ---------
#define NX (N_NODES * F_INN)
#define NW1 (3 * 128 * 192)
#define NW2 (3 * 192 * 192)
#define NW3 (3 * 192 * 128)
#define NPS (3 * N_GRAPHS * F_HID) /* pooled sums: x3, G1, G2 (layer 3) */
__global__ void k_convAll(const float* __restrict__ x, const float* __restrict__ W1,
                          const float* __restrict__ W2, const float* __restrict__ W3,
                          unsigned short* __restrict__ xb,
                          unsigned short* __restrict__ Wt1,
                          unsigned short* __restrict__ Wt2,
                          unsigned short* __restrict__ Wt3,
                          int* __restrict__ cnt, float* __restrict__ psum) {
    int idx = blockIdx.x * 256 + threadIdx.x;
    if (idx < NX) {
        xb[idx] = f2bf(x[idx]);
        return;
    }
    idx -= NX;
    if (idx < NW1) {  // W[j][k][n] -> Wt[j][n][k], Fin=128, Fout=192
        int per = 128 * 192;
        int j = idx / per, r = idx - j * per;
        int k = r / 192, n = r - k * 192;
        float v = (j == 0) ? (W1[idx] - W1[idx + 2 * per])
                           : (j == 2 ? 2.f * W1[idx] : W1[idx]);
        Wt1[j * per + n * 128 + k] = f2bf(v);
        return;
    }
    idx -= NW1;
    if (idx < NW2) {  // Fin=192, Fout=192
        int per = 192 * 192;
        int j = idx / per, r = idx - j * per;
        int k = r / 192, n = r - k * 192;
        float v = (j == 0) ? (W2[idx] - W2[idx + 2 * per])
                           : (j == 2 ? 2.f * W2[idx] : W2[idx]);
        Wt2[j * per + n * 192 + k] = f2bf(v);
        return;
    }
    idx -= NW2;
    if (idx < NW3) {  // Fin=192, Fout=128
        int per = 192 * 128;
        int j = idx / per, r = idx - j * per;
        int k = r / 128, n = r - k * 128;
        float v = (j == 0) ? (W3[idx] - W3[idx + 2 * per])
                           : (j == 2 ? 2.f * W3[idx] : W3[idx]);
        Wt3[j * per + n * 192 + k] = f2bf(v);
        return;
    }
    idx -= NW3;
    if (idx < N_NODES) {
        cnt[idx] = 0;
        return;
    }
    idx -= N_NODES;
    if (idx < NPS) psum[idx] = 0.f;
}

// ---------------- SpMV (bf16 in/out, fp32 accum): y = L_hat @ h -----------
// ROUND-14 LESSON: keep this kernel byte-identical to the proven form. No
// epilogues, no extra args, no shared variants. 41 µs @ 3.7 TB/s verified.
template <int F>
__global__ void k_spmv(const int* __restrict__ rp, const int2* __restrict__ cw,
                       const unsigned short* __restrict__ h,
                       unsigned short* __restrict__ y) {
    constexpr bool EX = (F > 128);
    constexpr int FU = F / 2;  // uints per row
    int wave = threadIdx.x >> 6;
    int lane = threadIdx.x & 63;
    int r = blockIdx.x * 4 + wave;
    if (r >= N_NODES) return;
    int e0 = __builtin_amdgcn_readfirstlane(rp[r]);
    int e1 = __builtin_amdgcn_readfirstlane(rp[r + 1]);
    const unsigned int* hu = (const unsigned int*)h;
    float a0 = 0.f, a1 = 0.f, a2 = 0.f;
    int e = e0;
    for (; e + 8 <= e1; e += 8) {
        int colv[8];
        float wv[8];
#pragma unroll
        for (int u = 0; u < 8; u++) {
            int2 p = cw[e + u];
            colv[u] = __builtin_amdgcn_readfirstlane(p.x);
            wv[u] = __uint_as_float(__builtin_amdgcn_readfirstlane(p.y));
        }
        unsigned int g[8];
        unsigned short s[8];
#pragma unroll
        for (int u = 0; u < 8; u++) {
            g[u] = hu[colv[u] * FU + lane];
            if constexpr (EX) s[u] = h[colv[u] * F + 128 + lane];
        }
#pragma unroll
        for (int u = 0; u < 8; u++) {
            a0 += wv[u] * bf2f((unsigned short)g[u]);
            a1 += wv[u] * bf2f((unsigned short)(g[u] >> 16));
            if constexpr (EX) a2 += wv[u] * bf2f(s[u]);
        }
    }
    for (; e + 4 <= e1; e += 4) {
        int colv[4];
        float wv[4];
#pragma unroll
        for (int u = 0; u < 4; u++) {
            int2 p = cw[e + u];
            colv[u] = __builtin_amdgcn_readfirstlane(p.x);
            wv[u] = __uint_as_float(__builtin_amdgcn_readfirstlane(p.y));
        }
        unsigned int g[4];
        unsigned short s[4];
#pragma unroll
        for (int u = 0; u < 4; u++) {
            g[u] = hu[colv[u] * FU + lane];
            if constexpr (EX) s[u] = h[colv[u] * F + 128 + lane];
        }
#pragma unroll
        for (int u = 0; u < 4; u++) {
            a0 += wv[u] * bf2f((unsigned short)g[u]);
            a1 += wv[u] * bf2f((unsigned short)(g[u] >> 16));
            if constexpr (EX) a2 += wv[u] * bf2f(s[u]);
        }
    }
    for (; e < e1; e++) {
        int2 p = cw[e];
        int c = __builtin_amdgcn_readfirstlane(p.x);
        float w = __uint_as_float(__builtin_amdgcn_readfirstlane(p.y));
        unsigned int g = hu[c * FU + lane];
        a0 += w * bf2f((unsigned short)g);
        a1 += w * bf2f((unsigned short)(g >> 16));
        if constexpr (EX) a2 += w * bf2f(h[c * F + 128 + lane]);
    }
    ((unsigned int*)y)[r * FU + lane] =
        (unsigned int)f2bf(a0) | ((unsigned int)f2bf(a1) << 16);
    if constexpr (EX) y[r * F + 128 + lane] = f2bf(a2);
}

// ---------------- fused 3-matrix bf16 MFMA GEMM (pristine round-3 form) ----
template <int Fin, int Fout>
__global__ __launch_bounds__(256) void k_gemm3(
    const unsigned short* __restrict__ A0, const unsigned short* __restrict__ A1,
    const unsigned short* __restrict__ A2, const unsigned short* __restrict__ Wt,
    const float* __restrict__ bias, unsigned short* __restrict__ C) {
    constexpr int NF = Fout / 16;  // N-fragments per wave row
    constexpr int BP = Fout / 64;  // B staging passes
    __shared__ unsigned short As[128 * 40];
    __shared__ unsigned short Bs[Fout * 40];
    int t = threadIdx.x;
    int w = t >> 6;
    int lane = t & 63;
    int ml = lane & 15;
    int quad = lane >> 4;
    int mBase = blockIdx.x * 128;
    constexpr int per = Fin * Fout;

    f32x4 acc[2][NF];
#pragma unroll
    for (int i = 0; i < 2; i++)
#pragma unroll
        for (int jn = 0; jn < NF; jn++) acc[i][jn] = (f32x4){0.f, 0.f, 0.f, 0.f};

    int srow = t >> 2;   // 0..63
    int schunk = t & 3;  // 16B chunk within 32-k slab
    constexpr int nChunks = (3 * Fin) >> 5;

    for (int ch = 0; ch < nChunks; ch++) {
        int kg = ch << 5;
        int j = kg / Fin;
        int kk = kg - j * Fin;
        const unsigned short* Aj = (j == 0) ? A0 : (j == 1) ? A1 : A2;
        if (ch > 0) __syncthreads();
#pragma unroll
        for (int pass = 0; pass < 2; pass++) {
            int row = srow + pass * 64;
            int gm = mBase + row;
            uint4 v = {0u, 0u, 0u, 0u};
            if (gm < N_NODES)
                v = *(const uint4*)(Aj + (size_t)gm * Fin + kk + schunk * 8);
            *(uint4*)&As[row * 40 + schunk * 8] = v;
        }
#pragma unroll
        for (int pass = 0; pass < BP; pass++) {
            int row = srow + pass * 64;  // n index 0..Fout-1
            const unsigned short* src =
                Wt + (size_t)j * per + (size_t)row * Fin + kk + schunk * 8;
            *(uint4*)&Bs[row * 40 + schunk * 8] = *(const uint4*)src;
        }
        __syncthreads();

        short8 afr[2];
#pragma unroll
        for (int i = 0; i < 2; i++)
            afr[i] = *(const short8*)&As[(w * 32 + i * 16 + ml) * 40 + quad * 8];
#pragma unroll
        for (int jn = 0; jn < NF; jn++) {
            short8 bfr = *(const short8*)&Bs[(jn * 16 + ml) * 40 + quad * 8];
#pragma unroll
            for (int i = 0; i < 2; i++)
                acc[i][jn] = __builtin_amdgcn_mfma_f32_16x16x32_bf16(
                    afr[i], bfr, acc[i][jn], 0, 0, 0);
        }
    }

    float biasv[NF];
#pragma unroll
    for (int jn = 0; jn < NF; jn++) biasv[jn] = bias[jn * 16 + ml];

#pragma unroll
    for (int i = 0; i < 2; i++) {
#pragma unroll
        for (int r = 0; r < 4; r++) {
            int m = mBase + w * 32 + i * 16 + quad * 4 + r;
            if (m < N_NODES) {
                unsigned short* cp = C + (size_t)m * Fout + ml;
#pragma unroll
                for (int jn = 0; jn < NF; jn++)
                    cp[jn * 16] = f2bf(acc[i][jn][r] + biasv[jn]);
            }
        }
    }
}

// ---------------- stream-pool of x3 and G1 (slots 0,1 of psum) -------------
// 782 blocks, wave owns 16 consecutive rows, batch preloaded once per wave
// and broadcast via shfl; ~1 flush per wave (6 lane-atomics each).
__global__ __launch_bounds__(256) void k_gpoolS(
    const unsigned short* __restrict__ x3, const unsigned short* __restrict__ g1,
    const int* __restrict__ batch, float* __restrict__ psum) {
    int wave = threadIdx.x >> 6;
    int lane = threadIdx.x & 63;
    int w0 = blockIdx.x * 64 + wave * 16;
    if (w0 >= N_NODES) return;
    int n = N_NODES - w0;
    if (n > 16) n = 16;
    int bv = 0;
    if (lane < 16 && w0 + lane < N_NODES) bv = batch[w0 + lane];
    const unsigned int* au = (const unsigned int*)x3;
    const unsigned int* bu = (const unsigned int*)g1;
    float a0 = 0.f, a1 = 0.f, a2 = 0.f, b0 = 0.f, b1 = 0.f, b2 = 0.f;
    int cur = __shfl(bv, 0);
    auto flush = [&](int g) {
        float* p0 = psum + (size_t)g * 192;  // slot 0: x3
        atomicAdd(&p0[2 * lane], a0);
        atomicAdd(&p0[2 * lane + 1], a1);
        atomicAdd(&p0[128 + lane], a2);
        float* p1 = p0 + (size_t)N_GRAPHS * 192;  // slot 1: G1
        atomicAdd(&p1[2 * lane], b0);
        atomicAdd(&p1[2 * lane + 1], b1);
        atomicAdd(&p1[128 + lane], b2);
    };
    for (int i = 0; i < n; i++) {
        int g = __shfl(bv, i);
        if (g != cur) {
            flush(cur);
            a0 = a1 = a2 = b0 = b1 = b2 = 0.f;
            cur = g;
        }
        size_t r = (size_t)(w0 + i);
        unsigned int va = au[r * 96 + lane];
        unsigned int vb = bu[r * 96 + lane];
        unsigned short sa = x3[r * 192 + 128 + lane];
        unsigned short sb = g1[r * 192 + 128 + lane];
        a0 += bf2f((unsigned short)va);
        a1 += bf2f((unsigned short)(va >> 16));
        a2 += bf2f(sa);
        b0 += bf2f((unsigned short)vb);
        b1 += bf2f((unsigned short)(vb >> 16));
        b2 += bf2f(sb);
    }
    flush(cur);
}

// ---------------- gather-pool: pool(G2) WITHOUT computing G2 ----------------
// pool_g(L·G1) = Σ_{edges e with row_e in g} w_e · G1[col_e]. CSR edge array
// is graph-sorted, so each wave takes a contiguous edge chunk, accumulates in
// registers (proven wave-uniform readfirstlane gather shape), flushes to psum
// slot 2 on (rare) graph changes via the u8 ge[] stream checked 8-at-a-time.
// ROUND-16 FIX: chunk 256 -> 64 edges/wave. 781 blocks (27% occupancy,
// 2.1 TB/s, 62 µs) was latency-bound; 64-edge chunks give 12500 waves /
// 3125 blocks — the SpMV's proven parallelism. Extra flush atomics (~2.4M
// over 12K addresses) cost far less than the occupancy recovery.
__global__ void k_gpool2(const int2* __restrict__ cw,
                         const unsigned char* __restrict__ ge,
                         const unsigned short* __restrict__ h,
                         float* __restrict__ psum2) {
    int wave = threadIdx.x >> 6;
    int lane = threadIdx.x & 63;
    int wid = blockIdx.x * 4 + wave;
    if (wid >= N_EDGES / 64) return;
    int eBeg = wid * 64;
    int eEnd = eBeg + 64;
    const unsigned int* hu = (const unsigned int*)h;
    float a0 = 0.f, a1 = 0.f, a2 = 0.f;
    int cur = __builtin_amdgcn_readfirstlane((int)ge[eBeg]);
    auto flush = [&](int g) {
        float* p = psum2 + (size_t)g * 192;
        atomicAdd(&p[2 * lane], a0);
        atomicAdd(&p[2 * lane + 1], a1);
        atomicAdd(&p[128 + lane], a2);
    };
    for (int e = eBeg; e < eEnd; e += 8) {
        uint2 gw = *(const uint2*)(ge + e);
        unsigned int lo = __builtin_amdgcn_readfirstlane(gw.x);
        unsigned int hi = __builtin_amdgcn_readfirstlane(gw.y);
        unsigned int rep = 0x01010101u * (unsigned int)cur;
        if (lo == rep && hi == rep) {
            // fast path: all 8 edges in current graph
            int colv[8];
            float wv[8];
#pragma unroll
            for (int u = 0; u < 8; u++) {
                int2 p = cw[e + u];
                colv[u] = __builtin_amdgcn_readfirstlane(p.x);
                wv[u] = __uint_as_float(__builtin_amdgcn_readfirstlane(p.y));
            }
            unsigned int g[8];
            unsigned short s[8];
#pragma unroll
            for (int u = 0; u < 8; u++) {
                g[u] = hu[colv[u] * 96 + lane];
                s[u] = h[colv[u] * 192 + 128 + lane];
            }
#pragma unroll
            for (int u = 0; u < 8; u++) {
                a0 += wv[u] * bf2f((unsigned short)g[u]);
                a1 += wv[u] * bf2f((unsigned short)(g[u] >> 16));
                a2 += wv[u] * bf2f(s[u]);
            }
        } else {
            // slow path (graph boundary inside this group): per-edge
            for (int u = 0; u < 8; u++) {
                unsigned int word = (u < 4) ? lo : hi;
                int g = (int)((word >> (8 * (u & 3))) & 0xFFu);
                if (g != cur) {
                    flush(cur);
                    a0 = a1 = a2 = 0.f;
                    cur = g;
                }
                int2 p = cw[e + u];
                int c = __builtin_amdgcn_readfirstlane(p.x);
                float w = __uint_as_float(__builtin_amdgcn_readfirstlane(p.y));
                unsigned int gv = hu[c * 96 + lane];
                a0 += w * bf2f((unsigned short)gv);
                a1 += w * bf2f((unsigned short)(gv >> 16));
                a2 += w * bf2f(h[c * 192 + 128 + lane]);
            }
        }
    }
    flush(cur);
}

// ---------------- head: pooled layer-3 reconstruction + fc + log_softmax --
__global__ __launch_bounds__(128) void k_head2(
    const float* __restrict__ psum,  // [3][64][192]: x3, G1, G2 sums
    const unsigned short* __restrict__ Wt3, const float* __restrict__ b3,
    const int* __restrict__ batch, const float* __restrict__ fcw,
    const float* __restrict__ fcb, float* __restrict__ out) {
    int g = blockIdx.x;
    int t = threadIdx.x;  // 128 threads = one output feature each
    __shared__ float ps[3 * 192];
    __shared__ float m3[F_OUTT];
    __shared__ float sl[N_CLS];
    for (int i = t; i < 192; i += 128) {
        ps[i] = psum[g * 192 + i];
        ps[192 + i] = psum[N_GRAPHS * 192 + g * 192 + i];
        ps[384 + i] = psum[2 * N_GRAPHS * 192 + g * 192 + i];
    }
    __syncthreads();
    int a = 0, b = N_NODES;
    while (a < b) { int m = (a + b) >> 1; if (batch[m] < g) a = m + 1; else b = m; }
    int lo = a;
    a = lo; b = N_NODES;
    while (a < b) { int m = (a + b) >> 1; if (batch[m] < g + 1) a = m + 1; else b = m; }
    float inv = 1.f / fmaxf((float)(a - lo), 1.f);
    constexpr int per = 192 * F_OUTT;
    float accv = 0.f;
    const unsigned short* wp = Wt3 + (size_t)t * 192;  // Wt3[j][n][k], n=t
#pragma unroll 4
    for (int k = 0; k < 192; k += 8) {
        short8 v0 = *(const short8*)(wp + k);
        short8 v1 = *(const short8*)(wp + per + k);
        short8 v2 = *(const short8*)(wp + 2 * per + k);
#pragma unroll
        for (int j = 0; j < 8; j++)
            accv += ps[k + j] * bf2f((unsigned short)v0[j]) +
                    ps[192 + k + j] * bf2f((unsigned short)v1[j]) +
                    ps[384 + k + j] * bf2f((unsigned short)v2[j]);
    }
    m3[t] = accv * inv + b3[t];
    __syncthreads();
    if (t < N_CLS) {
        float l = fcb[t];
        for (int n = 0; n < F_OUTT; n++) l += m3[n] * fcw[n * N_CLS + t];
        sl[t] = l;
    }
    __syncthreads();
    if (t < N_CLS) {
        float mx = -1e30f;
        for (int i = 0; i < N_CLS; i++) mx = fmaxf(mx, sl[i]);
        float s = 0.f;
        for (int i = 0; i < N_CLS; i++) s += expf(sl[i] - mx);
        out[g * N_CLS + t] = sl[t] - mx - logf(s);
    }
}

extern "C" void kernel_launch(void* const* d_in, const int* in_sizes, int n_in,
                              void* d_out, int out_size, void* d_ws, size_t ws_size,
                              hipStream_t stream) {
    const float* x = (const float*)d_in[0];
    const int* ei = (const int*)d_in[1];
    const int* batch = (const int*)d_in[2];
    const float* W1 = (const float*)d_in[3];
    const float* b1 = (const float*)d_in[4];
    const float* W2 = (const float*)d_in[5];
    const float* b2 = (const float*)d_in[6];
    const float* W3 = (const float*)d_in[7];
    const float* b3 = (const float*)d_in[8];
    const float* fcw = (const float*)d_in[9];
    const float* fcb = (const float*)d_in[10];
    float* out = (float*)d_out;
    const int* row = ei;
    const int* col = ei + N_EDGES;

    char* p = (char*)d_ws;
    auto carve = [&](size_t bytes) {
        char* q = p;
        p += (bytes + 255) & ~(size_t)255;
        return q;
    };
    int* cnt = (int*)carve(N_NODES * 4);
    int* rank = (int*)carve((size_t)N_EDGES * 4);
    float* dis = (float*)carve(N_NODES * 4);
    int* rp = (int*)carve((N_NODES + 1) * 4);
    int* part = (int*)carve(128 * 4);
    int2* cw = (int2*)carve((size_t)N_EDGES * 8);
    unsigned char* ge = (unsigned char*)carve((size_t)N_EDGES);
    unsigned short* xb = (unsigned short*)carve((size_t)N_NODES * F_INN * 2);
    size_t hbytes = (size_t)N_NODES * 192 * 2;
    unsigned short* bufA = (unsigned short*)carve(hbytes);
    unsigned short* bufB = (unsigned short*)carve(hbytes);
    unsigned short* bufC = (unsigned short*)carve(hbytes);
    unsigned short* bufD = (unsigned short*)carve(hbytes);
    unsigned short* Wt1 = (unsigned short*)carve(NW1 * 2);
    unsigned short* Wt2 = (unsigned short*)carve(NW2 * 2);
    unsigned short* Wt3 = (unsigned short*)carve(NW3 * 2);
    float* psum = (float*)carve(NPS * 4);  // [3][64][192]: x3, G1, G2

    // conv + zeroing first (replaces all memsets; stream order covers deps)
    {
        int tot = NX + NW1 + NW2 + NW3 + N_NODES + NPS;
        k_convAll<<<(tot + 255) / 256, 256, 0, stream>>>(x, W1, W2, W3, xb, Wt1, Wt2,
                                                         Wt3, cnt, psum);
    }

    k_deg<<<(N_EDGES + 255) / 256, 256, 0, stream>>>(row, cnt, rank);
    int nb = (N_NODES + 511) / 512;  // 98
    k_scan1<<<nb, 256, 0, stream>>>(cnt, rp, part, dis);
    k_scan3<<<nb, 256, 0, stream>>>(rp, part, nb);
    k_scatter<<<(N_EDGES + 255) / 256, 256, 0, stream>>>(row, col, dis, rp, rank,
                                                         batch, cw, ge);

    const int spmvGrid = (N_NODES + 3) / 4;
    const int gemmGrid = (N_NODES + 127) / 128;

    // Layer 1: G1 = L x, G2 = L G1; out = x(W0-W2) + G1 W1 + G2 (2W2) + b
    k_spmv<128><<<spmvGrid, 256, 0, stream>>>(rp, cw, xb, bufB);
    k_spmv<128><<<spmvGrid, 256, 0, stream>>>(rp, cw, bufB, bufC);
    k_gemm3<128, 192><<<gemmGrid, 256, 0, stream>>>(xb, bufB, bufC, Wt1, b1, bufA);
    // Layer 2
    k_spmv<192><<<spmvGrid, 256, 0, stream>>>(rp, cw, bufA, bufB);
    k_spmv<192><<<spmvGrid, 256, 0, stream>>>(rp, cw, bufB, bufC);
    k_gemm3<192, 192><<<gemmGrid, 256, 0, stream>>>(bufA, bufB, bufC, Wt2, b2, bufD);
    // Layer 3: mean-pool commutes with the Chebyshev combination.
    //   pool(x3), pool(G1): stream bufD/bufB.  pool(G2) = edge-gather over G1
    //   (no G2 materialization, SpMV#6 deleted).
    k_spmv<192><<<spmvGrid, 256, 0, stream>>>(rp, cw, bufD, bufB);
    k_gpoolS<<<(N_NODES + 63) / 64, 256, 0, stream>>>(bufD, bufB, batch, psum);
    k_gpool2<<<(N_EDGES / 64 + 3) / 4, 256, 0, stream>>>(
        cw, ge, bufB, psum + 2 * N_GRAPHS * 192);

    k_head2<<<N_GRAPHS, 128, 0, stream>>>(psum, Wt3, b3, batch, fcw, fcb, out);
}

// Round 8
// 456.083 us; speedup vs baseline: 1.0778x; 1.0778x over previous
//
#include <hip/hip_runtime.h>
#include <math.h>

#define N_NODES 50000
#define N_EDGES 800000
#define N_GRAPHS 64
#define F_INN 128
#define F_HID 192
#define F_OUTT 128
#define N_CLS 10

typedef short short8 __attribute__((ext_vector_type(8)));
typedef float f32x4 __attribute__((ext_vector_type(4)));

static __device__ inline unsigned short f2bf(float f) {
    unsigned int u = __float_as_uint(f);
    unsigned int r = (u + 0x7FFFu + ((u >> 16) & 1u)) >> 16;  // RNE
    return (unsigned short)r;
}
static __device__ inline float bf2f(unsigned short h) {
    return __uint_as_float(((unsigned int)h) << 16);
}

// ---------------- CSR build ----------------
// k_deg records each edge's rank (atomic return is free); scatter is then
// atomic-free. 1 edge/thread (TLP > ILP for random atomics — round-6 lesson).
__global__ void k_deg(const int* __restrict__ row, int* __restrict__ cnt,
                      int* __restrict__ rank) {
    int e = blockIdx.x * 256 + threadIdx.x;
    if (e < N_EDGES) rank[e] = atomicAdd(&cnt[row[e]], 1);
}

__global__ void k_scan1(const int* __restrict__ cnt, int* __restrict__ rp,
                        int* __restrict__ part, float* __restrict__ dis) {
    __shared__ int s[256];
    int base = blockIdx.x * 512;
    int i0 = base + 2 * threadIdx.x;
    int v0 = (i0 < N_NODES) ? cnt[i0] : 0;
    int v1 = (i0 + 1 < N_NODES) ? cnt[i0 + 1] : 0;
    if (i0 < N_NODES) dis[i0] = v0 > 0 ? rsqrtf((float)v0) : 0.f;
    if (i0 + 1 < N_NODES) dis[i0 + 1] = v1 > 0 ? rsqrtf((float)v1) : 0.f;
    int tsum = v0 + v1;
    s[threadIdx.x] = tsum;
    __syncthreads();
    for (int off = 1; off < 256; off <<= 1) {
        int val = (threadIdx.x >= off) ? s[threadIdx.x - off] : 0;
        __syncthreads();
        s[threadIdx.x] += val;
        __syncthreads();
    }
    int excl = s[threadIdx.x] - tsum;
    if (i0 < N_NODES) rp[i0] = excl;
    if (i0 + 1 < N_NODES) rp[i0 + 1] = excl + v0;
    if (threadIdx.x == 255) part[blockIdx.x] = s[255];
}

// scan phases 2+3 fused: each block reduces part[0..b-1] itself (nb<=128).
__global__ void k_scan3(int* __restrict__ rp, const int* __restrict__ part,
                        int nb) {
    __shared__ int s[128];
    int t = threadIdx.x;
    int b = blockIdx.x;
    if (t < 128) s[t] = (t < b && t < nb) ? part[t] : 0;
    __syncthreads();
    for (int off = 64; off > 0; off >>= 1) {
        if (t < off) s[t] += s[t + off];
        __syncthreads();
    }
    int add = s[0];
    int i0 = b * 512 + 2 * t;
    if (i0 < N_NODES) rp[i0] += add;
    if (i0 + 1 < N_NODES) rp[i0 + 1] += add;
    if (b == 0 && t == 0) rp[N_NODES] = N_EDGES;
}

// packed CSR payload: (col, weight-bits). Atomic-free: pos = rp[r] + rank[e].
// ROUND-13 LESSON: do NOT split into u16 col + dis[] recompute — the
// dependent dis[col] load adds an L2 round-trip on the per-edge critical
// path (3.7 -> 1.5 TB/s). One independent 8B wave-uniform load per edge.
__global__ void k_scatter(const int* __restrict__ row, const int* __restrict__ col,
                          const float* __restrict__ dis, const int* __restrict__ rp,
                          const int* __restrict__ rank, int2* __restrict__ cw) {
    int e = blockIdx.x * 256 + threadIdx.x;
    if (e < N_EDGES) {
        int r = row[e], c = col[e];
        int pos = rp[r] + rank[e];
        int2 v;
        v.x = c;
        v.y = __float_as_int(-dis[r] * dis[c]);
        cw[pos] = v;
    }
}

// ---------------- fused fp32->bf16 conversions + workspace zeroing ---------
// Chebyshev weight folding: out = Tx0(W0-W2) + G1*W1 + G2*(2*W2), where
// G1 = L*Tx0, G2 = L*G1 — SpMV needs no alpha/beta epilogues.
// Tail of the index space zeroes cnt and psum (replaces hipMemsetAsync).
#define NX (N_NODES * F_INN)
#define NW1 (3 * 128 * 192)
#define NW2 (3 * 192 * 192)
#define NW3 (3 * 192 * 128)
#define NPS (N_GRAPHS * F_OUTT)
__global__ void k_convAll(const float* __restrict__ x, const float* __restrict__ W1,
                          const float* __restrict__ W2, const float* __restrict__ W3,
                          unsigned short* __restrict__ xb,
                          unsigned short* __restrict__ Wt1,
                          unsigned short* __restrict__ Wt2,
                          unsigned short* __restrict__ Wt3,
                          int* __restrict__ cnt, float* __restrict__ psum) {
    int idx = blockIdx.x * 256 + threadIdx.x;
    if (idx < NX) {
        xb[idx] = f2bf(x[idx]);
        return;
    }
    idx -= NX;
    if (idx < NW1) {  // W[j][k][n] -> Wt[j][n][k], Fin=128, Fout=192
        int per = 128 * 192;
        int j = idx / per, r = idx - j * per;
        int k = r / 192, n = r - k * 192;
        float v = (j == 0) ? (W1[idx] - W1[idx + 2 * per])
                           : (j == 2 ? 2.f * W1[idx] : W1[idx]);
        Wt1[j * per + n * 128 + k] = f2bf(v);
        return;
    }
    idx -= NW1;
    if (idx < NW2) {  // Fin=192, Fout=192
        int per = 192 * 192;
        int j = idx / per, r = idx - j * per;
        int k = r / 192, n = r - k * 192;
        float v = (j == 0) ? (W2[idx] - W2[idx + 2 * per])
                           : (j == 2 ? 2.f * W2[idx] : W2[idx]);
        Wt2[j * per + n * 192 + k] = f2bf(v);
        return;
    }
    idx -= NW2;
    if (idx < NW3) {  // Fin=192, Fout=128
        int per = 192 * 128;
        int j = idx / per, r = idx - j * per;
        int k = r / 128, n = r - k * 128;
        float v = (j == 0) ? (W3[idx] - W3[idx + 2 * per])
                           : (j == 2 ? 2.f * W3[idx] : W3[idx]);
        Wt3[j * per + n * 192 + k] = f2bf(v);
        return;
    }
    idx -= NW3;
    if (idx < N_NODES) {
        cnt[idx] = 0;
        return;
    }
    idx -= N_NODES;
    if (idx < NPS) psum[idx] = 0.f;
}

// ---------------- SpMV (bf16 in/out, fp32 accum): y = L_hat @ h -----------
// One wave per row; lane l owns feats {2l,2l+1} (uint gather) + 128+l for
// F=192. Wave-uniform edge metadata via readfirstlane; unroll x8.
// NOTE (round 8): structural floor — FETCH == h-size x 8 XCDs (compulsory
// replication) at the ~3.7 TB/s fabric ceiling. Round 11 proved fusing this
// into a high-LDS/VGPR coop kernel collapses its occupancy (61%->24%) and
// 2.5x's total time — keep it standalone. ROUND-14: keep byte-identical; any
// grafted epilogue/templating regressed it 41->98 µs.
template <int F>
__global__ void k_spmv(const int* __restrict__ rp, const int2* __restrict__ cw,
                       const unsigned short* __restrict__ h,
                       unsigned short* __restrict__ y) {
    constexpr bool EX = (F > 128);
    constexpr int FU = F / 2;  // uints per row
    int wave = threadIdx.x >> 6;
    int lane = threadIdx.x & 63;
    int r = blockIdx.x * 4 + wave;
    if (r >= N_NODES) return;
    int e0 = __builtin_amdgcn_readfirstlane(rp[r]);
    int e1 = __builtin_amdgcn_readfirstlane(rp[r + 1]);
    const unsigned int* hu = (const unsigned int*)h;
    float a0 = 0.f, a1 = 0.f, a2 = 0.f;
    int e = e0;
    for (; e + 8 <= e1; e += 8) {
        int colv[8];
        float wv[8];
#pragma unroll
        for (int u = 0; u < 8; u++) {
            int2 p = cw[e + u];
            colv[u] = __builtin_amdgcn_readfirstlane(p.x);
            wv[u] = __uint_as_float(__builtin_amdgcn_readfirstlane(p.y));
        }
        unsigned int g[8];
        unsigned short s[8];
#pragma unroll
        for (int u = 0; u < 8; u++) {
            g[u] = hu[colv[u] * FU + lane];
            if constexpr (EX) s[u] = h[colv[u] * F + 128 + lane];
        }
#pragma unroll
        for (int u = 0; u < 8; u++) {
            a0 += wv[u] * bf2f((unsigned short)g[u]);
            a1 += wv[u] * bf2f((unsigned short)(g[u] >> 16));
            if constexpr (EX) a2 += wv[u] * bf2f(s[u]);
        }
    }
    for (; e + 4 <= e1; e += 4) {
        int colv[4];
        float wv[4];
#pragma unroll
        for (int u = 0; u < 4; u++) {
            int2 p = cw[e + u];
            colv[u] = __builtin_amdgcn_readfirstlane(p.x);
            wv[u] = __uint_as_float(__builtin_amdgcn_readfirstlane(p.y));
        }
        unsigned int g[4];
        unsigned short s[4];
#pragma unroll
        for (int u = 0; u < 4; u++) {
            g[u] = hu[colv[u] * FU + lane];
            if constexpr (EX) s[u] = h[colv[u] * F + 128 + lane];
        }
#pragma unroll
        for (int u = 0; u < 4; u++) {
            a0 += wv[u] * bf2f((unsigned short)g[u]);
            a1 += wv[u] * bf2f((unsigned short)(g[u] >> 16));
            if constexpr (EX) a2 += wv[u] * bf2f(s[u]);
        }
    }
    for (; e < e1; e++) {
        int2 p = cw[e];
        int c = __builtin_amdgcn_readfirstlane(p.x);
        float w = __uint_as_float(__builtin_amdgcn_readfirstlane(p.y));
        unsigned int g = hu[c * FU + lane];
        a0 += w * bf2f((unsigned short)g);
        a1 += w * bf2f((unsigned short)(g >> 16));
        if constexpr (EX) a2 += w * bf2f(h[c * F + 128 + lane]);
    }
    ((unsigned int*)y)[r * FU + lane] =
        (unsigned int)f2bf(a0) | ((unsigned int)f2bf(a1) << 16);
    if constexpr (EX) y[r * F + 128 + lane] = f2bf(a2);
}

// ---------------- fused 3-matrix bf16 MFMA GEMM ----------------
// C = A0@W'[0]+A1@W'[1]+A2@W'[2]+bias. One block owns the FULL Fout width
// (N-tiled grids re-read A across XCDs — compulsory fabric fills).
// Block: 256 thr = 4 waves; tile M=128 x N=Fout; wave = 32 rows.
// FUSE_POOL: skip the C write; pool the fp32 tile into psum instead
// (layer-3 output is consumed only by global mean pool). This is the ONLY
// cheap pooling site found in 6 rounds of alternatives (rounds 12-17): each
// wave pre-reduces 32 rows in-register -> ~200K atomics total; every
// standalone pooling kernel pays a 20-35 µs atomic/TLP tax.
template <int Fin, int Fout, bool FUSE_POOL>
__global__ __launch_bounds__(256) void k_gemm3(
    const unsigned short* __restrict__ A0, const unsigned short* __restrict__ A1,
    const unsigned short* __restrict__ A2, const unsigned short* __restrict__ Wt,
    const float* __restrict__ bias, unsigned short* __restrict__ C,
    const int* __restrict__ batch, float* __restrict__ psum) {
    constexpr int NF = Fout / 16;  // N-fragments per wave row
    constexpr int BP = Fout / 64;  // B staging passes
    __shared__ unsigned short As[128 * 40];
    __shared__ unsigned short Bs[Fout * 40];
    int t = threadIdx.x;
    int w = t >> 6;
    int lane = t & 63;
    int ml = lane & 15;
    int quad = lane >> 4;
    int mBase = blockIdx.x * 128;
    constexpr int per = Fin * Fout;

    f32x4 acc[2][NF];
#pragma unroll
    for (int i = 0; i < 2; i++)
#pragma unroll
        for (int jn = 0; jn < NF; jn++) acc[i][jn] = (f32x4){0.f, 0.f, 0.f, 0.f};

    int srow = t >> 2;   // 0..63
    int schunk = t & 3;  // 16B chunk within 32-k slab
    constexpr int nChunks = (3 * Fin) >> 5;

    for (int ch = 0; ch < nChunks; ch++) {
        int kg = ch << 5;
        int j = kg / Fin;
        int kk = kg - j * Fin;
        const unsigned short* Aj = (j == 0) ? A0 : (j == 1) ? A1 : A2;
        if (ch > 0) __syncthreads();
#pragma unroll
        for (int pass = 0; pass < 2; pass++) {
            int row = srow + pass * 64;
            int gm = mBase + row;
            uint4 v = {0u, 0u, 0u, 0u};
            if (gm < N_NODES)
                v = *(const uint4*)(Aj + (size_t)gm * Fin + kk + schunk * 8);
            *(uint4*)&As[row * 40 + schunk * 8] = v;
        }
#pragma unroll
        for (int pass = 0; pass < BP; pass++) {
            int row = srow + pass * 64;  // n index 0..Fout-1
            const unsigned short* src =
                Wt + (size_t)j * per + (size_t)row * Fin + kk + schunk * 8;
            *(uint4*)&Bs[row * 40 + schunk * 8] = *(const uint4*)src;
        }
        __syncthreads();

        short8 afr[2];
#pragma unroll
        for (int i = 0; i < 2; i++)
            afr[i] = *(const short8*)&As[(w * 32 + i * 16 + ml) * 40 + quad * 8];
#pragma unroll
        for (int jn = 0; jn < NF; jn++) {
            short8 bfr = *(const short8*)&Bs[(jn * 16 + ml) * 40 + quad * 8];
#pragma unroll
            for (int i = 0; i < 2; i++)
                acc[i][jn] = __builtin_amdgcn_mfma_f32_16x16x32_bf16(
                    afr[i], bfr, acc[i][jn], 0, 0, 0);
        }
    }

    float biasv[NF];
#pragma unroll
    for (int jn = 0; jn < NF; jn++) biasv[jn] = bias[jn * 16 + ml];

    if constexpr (!FUSE_POOL) {
#pragma unroll
        for (int i = 0; i < 2; i++) {
#pragma unroll
            for (int r = 0; r < 4; r++) {
                int m = mBase + w * 32 + i * 16 + quad * 4 + r;
                if (m < N_NODES) {
                    unsigned short* cp = C + (size_t)m * Fout + ml;
#pragma unroll
                    for (int jn = 0; jn < NF; jn++)
                        cp[jn * 16] = f2bf(acc[i][jn][r] + biasv[jn]);
                }
            }
        }
    } else {
        int m0 = mBase + w * 32;
        if (m0 >= N_NODES) return;
        int mlast = m0 + 31;
        if (mlast >= N_NODES) mlast = N_NODES - 1;
        int g0 = batch[m0];
        int g1 = batch[mlast];
        if (g0 == g1) {
            // fast path: whole wave in one graph
#pragma unroll
            for (int jn = 0; jn < NF; jn++) {
                float pv = 0.f;
#pragma unroll
                for (int i = 0; i < 2; i++)
#pragma unroll
                    for (int r = 0; r < 4; r++) {
                        int m = m0 + i * 16 + quad * 4 + r;
                        if (m < N_NODES) pv += acc[i][jn][r] + biasv[jn];
                    }
                pv += __shfl_xor(pv, 16);
                pv += __shfl_xor(pv, 32);
                if (lane < 16) atomicAdd(&psum[g0 * F_OUTT + ml + jn * 16], pv);
            }
        } else {
            // boundary wave: per-row atomics
#pragma unroll
            for (int i = 0; i < 2; i++)
#pragma unroll
                for (int r = 0; r < 4; r++) {
                    int m = m0 + i * 16 + quad * 4 + r;
                    if (m < N_NODES) {
                        int g = batch[m];
#pragma unroll
                        for (int jn = 0; jn < NF; jn++)
                            atomicAdd(&psum[g * F_OUTT + ml + jn * 16],
                                      acc[i][jn][r] + biasv[jn]);
                    }
                }
        }
    }
}

// ---------------- head: mean + fc + log_softmax ----------------
__global__ void k_head(const float* __restrict__ psum, const int* __restrict__ batch,
                       const float* __restrict__ fcw, const float* __restrict__ fcb,
                       float* __restrict__ out) {
    int g = blockIdx.x;
    int c = threadIdx.x;  // 64 threads, lanes >= N_CLS idle
    __shared__ float sl[N_CLS];
    int a = 0, b = N_NODES;
    while (a < b) { int m = (a + b) >> 1; if (batch[m] < g) a = m + 1; else b = m; }
    int lo = a;
    a = lo; b = N_NODES;
    while (a < b) { int m = (a + b) >> 1; if (batch[m] < g + 1) a = m + 1; else b = m; }
    float inv = 1.f / fmaxf((float)(a - lo), 1.f);
    float l = 0.f;
    if (c < N_CLS) {
        l = fcb[c];
        for (int k = 0; k < F_OUTT; k++)
            l += psum[g * F_OUTT + k] * inv * fcw[k * N_CLS + c];
        sl[c] = l;
    }
    __syncthreads();
    if (c < N_CLS) {
        float m = -1e30f;
        for (int i = 0; i < N_CLS; i++) m = fmaxf(m, sl[i]);
        float s = 0.f;
        for (int i = 0; i < N_CLS; i++) s += expf(sl[i] - m);
        out[g * N_CLS + c] = l - m - logf(s);
    }
}

extern "C" void kernel_launch(void* const* d_in, const int* in_sizes, int n_in,
                              void* d_out, int out_size, void* d_ws, size_t ws_size,
                              hipStream_t stream) {
    const float* x = (const float*)d_in[0];
    const int* ei = (const int*)d_in[1];
    const int* batch = (const int*)d_in[2];
    const float* W1 = (const float*)d_in[3];
    const float* b1 = (const float*)d_in[4];
    const float* W2 = (const float*)d_in[5];
    const float* b2 = (const float*)d_in[6];
    const float* W3 = (const float*)d_in[7];
    const float* b3 = (const float*)d_in[8];
    const float* fcw = (const float*)d_in[9];
    const float* fcb = (const float*)d_in[10];
    float* out = (float*)d_out;
    const int* row = ei;
    const int* col = ei + N_EDGES;

    char* p = (char*)d_ws;
    auto carve = [&](size_t bytes) {
        char* q = p;
        p += (bytes + 255) & ~(size_t)255;
        return q;
    };
    int* cnt = (int*)carve(N_NODES * 4);
    int* rank = (int*)carve((size_t)N_EDGES * 4);
    float* dis = (float*)carve(N_NODES * 4);
    int* rp = (int*)carve((N_NODES + 1) * 4);
    int* part = (int*)carve(128 * 4);
    int2* cw = (int2*)carve((size_t)N_EDGES * 8);
    unsigned short* xb = (unsigned short*)carve((size_t)N_NODES * F_INN * 2);
    size_t hbytes = (size_t)N_NODES * 192 * 2;
    unsigned short* bufA = (unsigned short*)carve(hbytes);
    unsigned short* bufB = (unsigned short*)carve(hbytes);
    unsigned short* bufC = (unsigned short*)carve(hbytes);
    unsigned short* bufD = (unsigned short*)carve(hbytes);
    unsigned short* Wt1 = (unsigned short*)carve(NW1 * 2);
    unsigned short* Wt2 = (unsigned short*)carve(NW2 * 2);
    unsigned short* Wt3 = (unsigned short*)carve(NW3 * 2);
    float* psum = (float*)carve(NPS * 4);

    // conv + zeroing first (replaces all memsets; stream order covers deps)
    {
        int tot = NX + NW1 + NW2 + NW3 + N_NODES + NPS;
        k_convAll<<<(tot + 255) / 256, 256, 0, stream>>>(x, W1, W2, W3, xb, Wt1, Wt2,
                                                         Wt3, cnt, psum);
    }

    k_deg<<<(N_EDGES + 255) / 256, 256, 0, stream>>>(row, cnt, rank);
    int nb = (N_NODES + 511) / 512;  // 98
    k_scan1<<<nb, 256, 0, stream>>>(cnt, rp, part, dis);
    k_scan3<<<nb, 256, 0, stream>>>(rp, part, nb);
    k_scatter<<<(N_EDGES + 255) / 256, 256, 0, stream>>>(row, col, dis, rp, rank, cw);

    const int spmvGrid = (N_NODES + 3) / 4;
    const int gemmGrid = (N_NODES + 127) / 128;

    // Layer 1: G1 = L x, G2 = L G1; out = x(W0-W2) + G1 W1 + G2 (2W2) + b
    k_spmv<128><<<spmvGrid, 256, 0, stream>>>(rp, cw, xb, bufB);
    k_spmv<128><<<spmvGrid, 256, 0, stream>>>(rp, cw, bufB, bufC);
    k_gemm3<128, 192, false><<<gemmGrid, 256, 0, stream>>>(xb, bufB, bufC, Wt1, b1,
                                                           bufA, batch, psum);
    // Layer 2
    k_spmv<192><<<spmvGrid, 256, 0, stream>>>(rp, cw, bufA, bufB);
    k_spmv<192><<<spmvGrid, 256, 0, stream>>>(rp, cw, bufB, bufC);
    k_gemm3<192, 192, false><<<gemmGrid, 256, 0, stream>>>(bufA, bufB, bufC, Wt2, b2,
                                                           bufD, batch, psum);
    // Layer 3: pool fused into epilogue; no C write
    k_spmv<192><<<spmvGrid, 256, 0, stream>>>(rp, cw, bufD, bufB);
    k_spmv<192><<<spmvGrid, 256, 0, stream>>>(rp, cw, bufB, bufC);
    k_gemm3<192, 128, true><<<gemmGrid, 256, 0, stream>>>(bufD, bufB, bufC, Wt3, b3,
                                                          nullptr, batch, psum);

    k_head<<<N_GRAPHS, 64, 0, stream>>>(psum, batch, fcw, fcb, out);
}